// Round 6
// baseline (73.813 us; speedup 1.0000x reference)
//
#include <hip/hip_runtime.h>
#include <math.h>

// Problem constants: inputs (128, 64, 64, 32) fp32
#define BB 128
#define NN 64
#define DD 2048            // 64*32
#define NBLK 512           // 4 blocks per batch, 16 rows each
#define NTHR 512           // 8 waves

__device__ __forceinline__ float wave_reduce_sum(float v) {
    #pragma unroll
    for (int off = 32; off > 0; off >>= 1)
        v += __shfl_down(v, off, 64);
    return v;
}

// Block g -> batch b = g>>2, quarter q = g&3 (rows q*16 .. q*16+15).
// Phase A: row norms of own rows. Phase B: column partial-sums over own rows
// (linear in rows -> no cross-block dependency). 4th block per batch combines
// quarter-vectors; 128th batch-finisher does the global tree. No grid sync,
// no spin: monotonic counters only.
__global__ __launch_bounds__(NTHR) void fused_loss_kernel(
        const float* __restrict__ x,
        float* __restrict__ vq,          // [512][2048] quarter column-sums
        float* __restrict__ diag_part,   // [512]
        double* __restrict__ partials,   // [128]
        unsigned* __restrict__ bcnt,     // [128]
        unsigned* __restrict__ gcnt,     // [1]
        float* __restrict__ out) {
    const int g = blockIdx.x;
    const int b = g >> 2, q = g & 3;
    const int t = threadIdx.x;
    const int lane = t & 63, wid = t >> 6;   // 8 waves

    __shared__ float invs[16];
    __shared__ float diag_w[8];
    __shared__ float red[8];
    __shared__ int flag;
    __shared__ double sd[BB];

    const float* xb = x + ((size_t)b * NN + q * 16) * DD;

    // ---- Phase A: wave w -> local rows 2w, 2w+1 ----
    float diag = 0.f;
    #pragma unroll
    for (int rr = 0; rr < 2; ++rr) {
        const int row = wid * 2 + rr;
        const float4* p = reinterpret_cast<const float4*>(xb + (size_t)row * DD);
        float s = 0.f;
        #pragma unroll
        for (int j = 0; j < 8; ++j) {          // 512 float4 per row
            float4 a = p[lane + 64 * j];
            s += a.x * a.x + a.y * a.y + a.z * a.z + a.w * a.w;
        }
        s = wave_reduce_sum(s);
        if (lane == 0) {
            float r = fmaxf(sqrtf(s), 1e-12f);
            float inv = 1.0f / r;
            invs[row] = inv;
            diag += s * inv * inv;             // ||att_row||^2
        }
    }
    if (lane == 0) diag_w[wid] = diag;
    __syncthreads();

    // ---- Phase B: thread t owns columns 4t..4t+3 over own 16 rows (L2-hot) ----
    {
        const float4* x4 = reinterpret_cast<const float4*>(xb);
        float4 v = make_float4(0.f, 0.f, 0.f, 0.f);
        #pragma unroll
        for (int n = 0; n < 16; ++n) {
            float4 a = x4[(size_t)n * (DD / 4) + t];
            const float iv = invs[n];
            v.x = fmaf(a.x, iv, v.x);
            v.y = fmaf(a.y, iv, v.y);
            v.z = fmaf(a.z, iv, v.z);
            v.w = fmaf(a.w, iv, v.w);
        }
        reinterpret_cast<float4*>(vq + (size_t)g * DD)[t] = v;
    }
    if (t == 0) {
        float dsum = 0.f;
        #pragma unroll
        for (int w = 0; w < 8; ++w) dsum += diag_w[w];
        diag_part[g] = dsum;
        __threadfence();                       // publish vq + diag (agent scope)
        unsigned old = __hip_atomic_fetch_add(&bcnt[b], 1u,
                        __ATOMIC_ACQ_REL, __HIP_MEMORY_SCOPE_AGENT);
        flag = (old == 3u);
    }
    __syncthreads();
    if (!flag) return;

    // ---- Batch finisher: v_b = sum of 4 quarter-vectors; sp = ||v_b||^2 ----
    {
        float vx = 0.f, vy = 0.f, vz = 0.f, vw = 0.f;
        #pragma unroll
        for (int qq = 0; qq < 4; ++qq) {
            const float* src = vq + ((size_t)(b * 4 + qq)) * DD + 4 * t;
            vx += __hip_atomic_load(src + 0, __ATOMIC_RELAXED, __HIP_MEMORY_SCOPE_AGENT);
            vy += __hip_atomic_load(src + 1, __ATOMIC_RELAXED, __HIP_MEMORY_SCOPE_AGENT);
            vz += __hip_atomic_load(src + 2, __ATOMIC_RELAXED, __HIP_MEMORY_SCOPE_AGENT);
            vw += __hip_atomic_load(src + 3, __ATOMIC_RELAXED, __HIP_MEMORY_SCOPE_AGENT);
        }
        float p = vx * vx + vy * vy + vz * vz + vw * vw;
        p = wave_reduce_sum(p);
        if (lane == 0) red[wid] = p;
    }
    __syncthreads();
    if (t == 0) {
        double sp = 0.0, dp = 0.0;
        #pragma unroll
        for (int w = 0; w < 8; ++w) sp += (double)red[w];
        #pragma unroll
        for (int qq = 0; qq < 4; ++qq)
            dp += (double)__hip_atomic_load(&diag_part[b * 4 + qq],
                        __ATOMIC_RELAXED, __HIP_MEMORY_SCOPE_AGENT);
        __hip_atomic_store(&partials[b], sp - dp,
                        __ATOMIC_RELEASE, __HIP_MEMORY_SCOPE_AGENT);
        unsigned old = __hip_atomic_fetch_add(gcnt, 1u,
                        __ATOMIC_ACQ_REL, __HIP_MEMORY_SCOPE_AGENT);
        flag = (old == (unsigned)(BB - 1)) ? 1 : 0;
    }
    __syncthreads();
    if (!flag) return;

    // ---- Global finisher: fixed-order tree over 128 batch partials ----
    if (t < BB)
        sd[t] = __hip_atomic_load(&partials[t],
                        __ATOMIC_RELAXED, __HIP_MEMORY_SCOPE_AGENT);
    __syncthreads();
    #pragma unroll
    for (int off = BB / 2; off > 0; off >>= 1) {
        if (t < off) sd[t] += sd[t + off];
        __syncthreads();
    }
    if (t == 0) out[0] = (float)(sd[0] / (double)BB);
}

extern "C" void kernel_launch(void* const* d_in, const int* in_sizes, int n_in,
                              void* d_out, int out_size, void* d_ws, size_t ws_size,
                              hipStream_t stream) {
    const float* x = (const float*)d_in[0];
    float* out = (float*)d_out;
    char* ws = (char*)d_ws;

    float* vq         = (float*)ws;                  // 512*2048*4 B = 4 MB
    float* diag_part  = (float*)(ws + 4194304);      // 2 KB
    double* partials  = (double*)(ws + 4196352);     // 1 KB (8B aligned)
    unsigned* bcnt    = (unsigned*)(ws + 4197376);   // 512 B
    unsigned* gcnt    = (unsigned*)(ws + 4197888);   // 4 B

    hipMemsetAsync(ws + 4197376, 0, 516, stream);    // zero both counters
    fused_loss_kernel<<<NBLK, NTHR, 0, stream>>>(x, vq, diag_part, partials,
                                                 bcnt, gcnt, out);
}

// Round 7
// 35.295 us; speedup vs baseline: 2.0913x; 2.0913x over previous
//
#include <hip/hip_runtime.h>
#include <math.h>

// Problem constants: inputs (128, 64, 64, 32) fp32
#define BB 128
#define NN 64
#define DD 2048            // 64*32
#define NBLK 256           // block u: batch b=u&127, half h=u>>7 (siblings same XCD)
#define NTHR 1024          // 16 waves

__device__ __forceinline__ float wave_reduce_sum(float v) {
    #pragma unroll
    for (int off = 32; off > 0; off >>= 1)
        v += __shfl_down(v, off, 64);
    return v;
}

// Fence-free fused kernel. Only RELAXED atomics (no buffer_wbl2/buffer_inv
// L2 flushes -- those were the 76us floor in R5/R6). Cross-block handshake:
// inv values double as ready-flags (inv > 0 always; buffer pre-zeroed).
__global__ __launch_bounds__(NTHR) void fused_loss_kernel(
        const float* __restrict__ x,
        float* __restrict__ inv_r,      // [128][64] pre-zeroed: 0 == not ready
        double* __restrict__ spB,       // [256] per-block partials
        unsigned* __restrict__ counter, // pre-zeroed
        float* __restrict__ out) {
    const unsigned u = blockIdx.x;
    const int b = (int)(u & 127u);
    const int h = (int)(u >> 7);        // row-half for phase A, col-half for phase B
    const int t = threadIdx.x;
    const int lane = t & 63, wid = t >> 6;   // 16 waves

    __shared__ float invs[NN];
    __shared__ float diag_w[16];
    __shared__ float red[16];
    __shared__ int flag;
    __shared__ double sd[NBLK];

    const float* xb = x + (size_t)b * NN * DD;

    // ---- Phase A: own 32 rows (h*32 ..), wave w -> rows 2w, 2w+1 ----
    float diag = 0.f;
    #pragma unroll
    for (int rr = 0; rr < 2; ++rr) {
        const int row = h * 32 + wid * 2 + rr;
        const float4* p = reinterpret_cast<const float4*>(xb + (size_t)row * DD);
        float s = 0.f;
        #pragma unroll
        for (int j = 0; j < 8; ++j) {          // 512 float4 per row
            float4 a = p[lane + 64 * j];
            s += a.x * a.x + a.y * a.y + a.z * a.z + a.w * a.w;
        }
        s = wave_reduce_sum(s);
        if (lane == 0) {
            float r = fmaxf(sqrtf(s), 1e-12f);
            float inv = 1.0f / r;               // > 0 always -> usable as flag
            invs[row] = inv;
            __hip_atomic_store(&inv_r[b * NN + row], inv,
                               __ATOMIC_RELAXED, __HIP_MEMORY_SCOPE_AGENT);
            diag += s * inv * inv;              // ||att_row||^2
        }
    }
    if (lane == 0) diag_w[wid] = diag;

    // ---- Sibling exchange: spin on relaxed loads (value==0 -> not ready) ----
    if (t < 32) {
        const int srow = (1 - h) * 32 + t;
        const float* addr = inv_r + b * NN + srow;
        float v;
        do {
            v = __hip_atomic_load(addr, __ATOMIC_RELAXED, __HIP_MEMORY_SCOPE_AGENT);
        } while (v == 0.f);
        invs[srow] = v;
    }
    __syncthreads();

    // ---- Phase B: column h*1024 + t over all 64 rows (own + sibling L2) ----
    {
        const float* xc = xb + h * 1024 + t;
        float v0 = 0.f, v1 = 0.f;               // 2 chains for ILP
        #pragma unroll 8
        for (int n = 0; n < NN; n += 2) {
            v0 = fmaf(xc[(size_t)n * DD],       invs[n],     v0);
            v1 = fmaf(xc[(size_t)(n + 1) * DD], invs[n + 1], v1);
        }
        const float v = v0 + v1;
        float p = wave_reduce_sum(v * v);
        if (lane == 0) red[wid] = p;
    }
    __syncthreads();

    if (t == 0) {
        double sp = 0.0, dp = 0.0;
        #pragma unroll
        for (int w = 0; w < 16; ++w) { sp += (double)red[w]; dp += (double)diag_w[w]; }
        __hip_atomic_store(&spB[u], sp - dp,
                           __ATOMIC_RELAXED, __HIP_MEMORY_SCOPE_AGENT);
        // Order my spB store at the coherence point BEFORE the counter bump.
        // This is a wave-local drain, not an L2 flush -- no fence cost.
        asm volatile("s_waitcnt vmcnt(0)" ::: "memory");
        unsigned old = __hip_atomic_fetch_add(counter, 1u,
                        __ATOMIC_RELAXED, __HIP_MEMORY_SCOPE_AGENT);
        flag = (old == NBLK - 1u) ? 1 : 0;
    }
    __syncthreads();
    if (!flag) return;

    // ---- Last block: deterministic fixed-order tree over 256 partials ----
    if (t < NBLK)
        sd[t] = __hip_atomic_load(&spB[t],
                        __ATOMIC_RELAXED, __HIP_MEMORY_SCOPE_AGENT);
    __syncthreads();
    #pragma unroll
    for (int off = NBLK / 2; off > 0; off >>= 1) {
        if (t < off) sd[t] += sd[t + off];
        __syncthreads();
    }
    if (t == 0) out[0] = (float)(sd[0] / (double)BB);
}

extern "C" void kernel_launch(void* const* d_in, const int* in_sizes, int n_in,
                              void* d_out, int out_size, void* d_ws, size_t ws_size,
                              hipStream_t stream) {
    const float* x = (const float*)d_in[0];
    float* out = (float*)d_out;
    char* ws = (char*)d_ws;

    float* inv_r      = (float*)ws;                 // 32 KB  [0, 32768)
    double* spB       = (double*)(ws + 32768);      // 2 KB   [32768, 34816)
    unsigned* counter = (unsigned*)(ws + 34816);    // 4 B

    // zero inv_r (ready-flags), spB, counter -- re-done every replay
    hipMemsetAsync(ws, 0, 34820, stream);
    fused_loss_kernel<<<NBLK, NTHR, 0, stream>>>(x, inv_r, spB, counter, out);
}